// Round 1
// baseline (664.646 us; speedup 1.0000x reference)
//
#include <hip/hip_runtime.h>

// Adaptive avg pool 64x64 -> 6x6, fp32, N=16, C=2048.
// Bin edges (compile-time): starts floor(i*64/6), ends ceil((i+1)*64/6)
//   edges: {0,10,21,32,42,53} .. {11,22,32,43,54,64}, widths 11/12.
// One block per (n,c) plane; plane staged in LDS (stride 68 pad: keeps
// float4 16B alignment (68%4==0) and scatters banks (4h mod 32) for phase 2).

#define H_IN 64
#define W_IN 64
#define H_OUT 6
#define W_OUT 6
#define LDS_STRIDE 68   // 64 + 4 pad

__global__ __launch_bounds__(256)
void adaptive_pool_kernel(const float* __restrict__ x, float* __restrict__ out) {
    __shared__ float tile[H_IN * LDS_STRIDE];      // 17408 B
    __shared__ float rowsum[H_IN][W_OUT];          // 1536 B

    const int plane = blockIdx.x;                  // n*C + c
    const float* __restrict__ src = x + (size_t)plane * (H_IN * W_IN);
    const int tid = threadIdx.x;

    // ---- Phase 1: coalesced float4 load of the 16 KiB plane into LDS ----
    const float4* __restrict__ src4 = (const float4*)src;
    #pragma unroll
    for (int k = 0; k < 4; ++k) {
        int f = tid + k * 256;          // float4 index within plane, 0..1023
        int h = f >> 4;                 // 16 float4 per row
        int w = (f & 15) << 2;
        float4 v = src4[f];
        // (68*h + w) % 4 == 0  -> 16B-aligned LDS write
        *(float4*)&tile[h * LDS_STRIDE + w] = v;
    }
    __syncthreads();

    // bin edges (same for H and W since 64->6 both dims)
    const int bs[6] = {0, 10, 21, 32, 42, 53};
    const int be[6] = {11, 22, 32, 43, 54, 64};

    // ---- Phase 2a: per-row w-bin sums: rowsum[h][j] ----
    for (int task = tid; task < H_IN * W_OUT; task += 256) {
        int h = task / W_OUT;
        int j = task - h * W_OUT;
        const float* row = &tile[h * LDS_STRIDE];
        float s = 0.f;
        for (int w = bs[j]; w < be[j]; ++w)
            s += row[w];
        rowsum[h][j] = s;
    }
    __syncthreads();

    // ---- Phase 2b: reduce rows into each of the 36 output bins ----
    if (tid < H_OUT * W_OUT) {
        int i = tid / W_OUT;
        int j = tid - i * W_OUT;
        float s = 0.f;
        for (int h = bs[i]; h < be[i]; ++h)
            s += rowsum[h][j];
        float scale = 1.0f / (float)((be[i] - bs[i]) * (be[j] - bs[j]));
        out[(size_t)plane * (H_OUT * W_OUT) + tid] = s * scale;
    }
}

extern "C" void kernel_launch(void* const* d_in, const int* in_sizes, int n_in,
                              void* d_out, int out_size, void* d_ws, size_t ws_size,
                              hipStream_t stream) {
    const float* x = (const float*)d_in[0];
    float* out = (float*)d_out;
    const int n_planes = in_sizes[0] / (H_IN * W_IN);   // 16*2048 = 32768
    adaptive_pool_kernel<<<n_planes, 256, 0, stream>>>(x, out);
}